// Round 11
// baseline (485.494 us; speedup 1.0000x reference)
//
#include <hip/hip_runtime.h>
#include <hip/hip_bf16.h>
#include <math.h>

#define NEG_SLOPE 0.2f
#define BN_EPS 1e-5f

typedef short bf16x8 __attribute__((ext_vector_type(8)));
typedef float f32x4 __attribute__((ext_vector_type(4)));

// ---- bf16 helpers (raw ushort payload) ------------------------------------
__device__ __forceinline__ float bf2f(unsigned short u) {
  union { unsigned int i; float f; } v;
  v.i = ((unsigned int)u) << 16;
  return v.f;
}
__device__ __forceinline__ unsigned short f2bf(float f) {
  union { unsigned int i; float f; } v;
  v.f = f;
  unsigned int i = v.i;
  unsigned int r = (i + 0x7fffu + ((i >> 16) & 1u)) >> 16;  // RNE
  return (unsigned short)r;
}

// ---------------------------------------------------------------------------
// Dtype detection: flags[0]=1 if floats are bf16; flags[1]=1 if idx int64.
// ---------------------------------------------------------------------------
__global__ __launch_bounds__(256) void detect_kernel(
    const unsigned int* __restrict__ xw, const unsigned int* __restrict__ eiw,
    int E, int* __restrict__ flags) {
  __shared__ int cnt[2];
  if (threadIdx.x < 2) cnt[threadIdx.x] = 0;
  __syncthreads();
  int t = threadIdx.x;
  int inrange = 0;
  for (int i = t; i < 2048; i += 256) {
    unsigned int e = (xw[i] >> 7) & 0xFFu;
    inrange += (e >= 100u && e <= 135u) ? 1 : 0;
  }
  atomicAdd(&cnt[0], inrange);
  int M = min(1024, E / 2);
  int zeros = 0;
  for (int i = t; i < M; i += 256) zeros += (eiw[2 * i + 1] == 0u) ? 1 : 0;
  atomicAdd(&cnt[1], zeros);
  __syncthreads();
  if (t == 0) {
    flags[0] = (cnt[0] > 1536) ? 1 : 0;
    flags[1] = (cnt[1] > M / 2) ? 1 : 0;
  }
}

// Vectorized x canonicalization: 8 elems/thread (16-B bf16 stores).
__global__ __launch_bounds__(256) void canon_x8(
    const void* __restrict__ src, unsigned short* __restrict__ dst, int n_real,
    int n_total, const int* __restrict__ flags) {
  int i = (blockIdx.x * 256 + threadIdx.x) * 8;
  if (i >= n_total) return;
  union { bf16x8 v; unsigned short u[8]; } o;
  if (i < n_real) {
    if (flags[0]) {
      o.v = *(const bf16x8*)((const unsigned short*)src + i);
    } else {
      const float4* f = (const float4*)((const float*)src + i);
      float4 f0 = f[0];
      float4 f1 = f[1];
      o.u[0] = f2bf(f0.x); o.u[1] = f2bf(f0.y);
      o.u[2] = f2bf(f0.z); o.u[3] = f2bf(f0.w);
      o.u[4] = f2bf(f1.x); o.u[5] = f2bf(f1.y);
      o.u[6] = f2bf(f1.z); o.u[7] = f2bf(f1.w);
    }
  } else {
#pragma unroll
    for (int j = 0; j < 8; ++j) o.u[j] = 0;
  }
  *(bf16x8*)(dst + i) = o.v;
}

// W [K][N] -> Wt [N][K] bf16.
__global__ __launch_bounds__(256) void canon_w_t(
    const void* __restrict__ src, unsigned short* __restrict__ dst, int Kdim,
    int Ndim, const int* __restrict__ flags) {
  int i = blockIdx.x * 256 + threadIdx.x;
  if (i >= Kdim * Ndim) return;
  int k = i / Ndim, n = i - k * Ndim;
  unsigned short v = flags[0] ? ((const unsigned short*)src)[i]
                              : f2bf(((const float*)src)[i]);
  dst[(size_t)n * Kdim + k] = v;
}

__global__ __launch_bounds__(1024) void canon_params(
    const void* s0, const void* s1, const void* s2, const void* s3,
    const void* s4, const void* s5, const void* s6, const void* s7,
    unsigned short* d0, unsigned short* d1, unsigned short* d2,
    unsigned short* d3, unsigned short* d4, unsigned short* d5,
    unsigned short* d6, unsigned short* d7, const int* __restrict__ flags) {
  int b = blockIdx.x, t = threadIdx.x;
  const void* s;
  unsigned short* d;
  int n;
  switch (b) {
    case 0: s = s0; d = d0; n = 1024; break;
    case 1: s = s1; d = d1; n = 1024; break;
    case 2: s = s2; d = d2; n = 1024; break;
    case 3: s = s3; d = d3; n = 1024; break;
    case 4: s = s4; d = d4; n = 1024; break;
    case 5: s = s5; d = d5; n = 128; break;
    case 6: s = s6; d = d6; n = 128; break;
    default: s = s7; d = d7; n = 128; break;
  }
  if (t < n)
    d[t] = flags[0] ? ((const unsigned short*)s)[t]
                    : f2bf(((const float*)s)[t]);
}

__global__ __launch_bounds__(256) void canon_idx(
    const int* __restrict__ ei, int* __restrict__ eis, int* __restrict__ eid,
    int E, const int* __restrict__ flags) {
  int e = blockIdx.x * 256 + threadIdx.x;
  if (e >= E) return;
  if (flags[1]) {
    eis[e] = ei[2 * (size_t)e];
    eid[e] = ei[2 * (size_t)E + 2 * (size_t)e];
  } else {
    eis[e] = ei[e];
    eid[e] = ei[E + e];
  }
}

// ---------------------------------------------------------------------------
// score_v: v_src[k][h] = sum_c W1[k][h*128+c] * a_src[h*128+c]  (fp32).
// s_src = h1 . a_src = x . v_src by linearity -> scores never need h1.
// One block, 128 threads (thread = input dim k, reads W1 row k contiguous).
// ---------------------------------------------------------------------------
__global__ __launch_bounds__(128) void score_v(
    const void* __restrict__ W1raw, const unsigned short* __restrict__ as1,
    const unsigned short* __restrict__ ad1, float* __restrict__ vsrc,
    float* __restrict__ vdst, const int* __restrict__ flags) {
  __shared__ float aS[1024], aD[1024];
  int t = threadIdx.x;
  for (int j = t; j < 1024; j += 128) {
    aS[j] = bf2f(as1[j]);
    aD[j] = bf2f(ad1[j]);
  }
  __syncthreads();
  const int isbf = flags[0];
#pragma unroll
  for (int h = 0; h < 8; ++h) {
    float s = 0.f, d = 0.f;
    for (int j = 0; j < 128; ++j) {
      int idx = h * 128 + j;
      float w = isbf ? bf2f(((const unsigned short*)W1raw)[(size_t)t * 1024 + idx])
                     : ((const float*)W1raw)[(size_t)t * 1024 + idx];
      s = fmaf(w, aS[idx], s);
      d = fmaf(w, aD[idx], d);
    }
    vsrc[t * 8 + h] = s;
    vdst[t * 8 + h] = d;
  }
}

// ---------------------------------------------------------------------------
// score_apply: ssrc/sdst[n][8] = x[n,:] @ v[:, h].  16 nodes x 16 outputs
// per 256-thread block; v (8 KB) in LDS; x rows via L1.
// ---------------------------------------------------------------------------
__global__ __launch_bounds__(256) void score_apply(
    const unsigned short* __restrict__ xbf, const float* __restrict__ vsrc,
    const float* __restrict__ vdst, float* __restrict__ ssrc,
    float* __restrict__ sdst, int N) {
  __shared__ float vS[128][8];
  __shared__ float vD[128][8];
  int t = threadIdx.x;
  for (int j = t; j < 1024; j += 256) {
    ((float*)vS)[j] = vsrc[j];
    ((float*)vD)[j] = vdst[j];
  }
  __syncthreads();
  int node = blockIdx.x * 16 + (t >> 4);
  if (node >= N) return;
  int o = t & 15;
  int h = o & 7;
  const unsigned short* xr = xbf + (size_t)node * 128;
  float s = 0.f;
  if (o < 8) {
    for (int k0 = 0; k0 < 128; k0 += 8) {
      union { bf16x8 v; unsigned short u[8]; } xv;
      xv.v = *(const bf16x8*)(xr + k0);
#pragma unroll
      for (int e = 0; e < 8; ++e) s = fmaf(bf2f(xv.u[e]), vS[k0 + e][h], s);
    }
    ssrc[(size_t)node * 8 + h] = s;
  } else {
    for (int k0 = 0; k0 < 128; k0 += 8) {
      union { bf16x8 v; unsigned short u[8]; } xv;
      xv.v = *(const bf16x8*)(xr + k0);
#pragma unroll
      for (int e = 0; e < 8; ++e) s = fmaf(bf2f(xv.u[e]), vD[k0 + e][h], s);
    }
    sdst[(size_t)node * 8 + h] = s;
  }
}

// ---------------------------------------------------------------------------
// agg1_fused: the layer-1 restructure. By linearity,
//   h1n[n] = (sum_e alpha_e x[src_e]) @ W1 + b1,
// so we gather 256-B x rows (not 2-KB h1 rows) and never materialize h1.
// Block = 64 nodes x 2 heads (bid&3 = head-pair; minor index -> one
// head-pair per XCD -> W1t panel stays L2-hot).
// Phase 1: wave w aggregates nodes w*16..+15 (lane = channel pair, 4-B
// gather, 2-edge pipeline, inline alpha from interleaved scores), then
// normalizes and writes bf16 into swizzled 32-KB LDS tile.
// Phase 2: tile @ W1t panel (B-in-regs 16 KB/wave, issued at kernel start),
// + bias -> h1n.  Pad nodes (n>=N) write b1 rows (finite, unused).
// ---------------------------------------------------------------------------
__global__ __launch_bounds__(256) void agg1_fused(
    const int* __restrict__ offsets, const int* __restrict__ srcs,
    const unsigned short* __restrict__ xbf,   // [MP][128]
    const float* __restrict__ ssrc, const float* __restrict__ sdst,  // [MP][8]
    const unsigned short* __restrict__ Bt,    // W1t [1024][128]
    const unsigned short* __restrict__ b1,    // [1024]
    unsigned short* __restrict__ h1n,         // [MP][1024]
    int N) {
  __shared__ unsigned short aggT[64 * 256];  // 32 KB: [node][head_l][128ch] swz

  const int tid = threadIdx.x;
  const int wid = tid >> 6;
  const int lane = tid & 63;
  const int q = lane >> 4;
  const int r = lane & 15;
  const int bid = blockIdx.x;
  const int m0 = (bid >> 2) * 64;
  const int h0 = (bid & 3) * 2;

  // Phase-2 operand: wave covers head hl=wid>>1, col half (wid&1)*64.
  const int hl = wid >> 1;
  const int hg = h0 + hl;
  const int colh = (wid & 1) * 64;
  bf16x8 bfr[4][4];
#pragma unroll
  for (int ni = 0; ni < 4; ++ni)
#pragma unroll
    for (int ks = 0; ks < 4; ++ks)
      bfr[ni][ks] = *(const bf16x8*)(
          Bt + (size_t)(hg * 128 + colh + ni * 16 + r) * 128 +
          (ks * 4 + q) * 8);

  // ---- Phase 1: aggregate weighted x rows ----
  const int c = lane * 2;  // channel pair
  const int g = lane >> 2;        // 8-elem granule 0..15
  const int e = (lane & 3) * 2;   // elem within granule
#pragma unroll 1
  for (int i = 0; i < 16; ++i) {
    int nl = wid * 16 + i;
    int n = m0 + nl;
    float aA0 = 0.f, aA1 = 0.f, aB0 = 0.f, aB1 = 0.f;
    float wsA = 0.f, wsB = 0.f;
    if (n < N) {
      int beg = offsets[n], end = offsets[n + 1];
      float2 sdp = *(const float2*)(sdst + (size_t)n * 8 + h0);
      int p = beg;
      for (; p + 2 <= end; p += 2) {
        int s0 = srcs[p], s1 = srcs[p + 1];
        float2 sp0 = *(const float2*)(ssrc + (size_t)s0 * 8 + h0);
        float2 sp1 = *(const float2*)(ssrc + (size_t)s1 * 8 + h0);
        unsigned int u0 = *(const unsigned int*)(xbf + (size_t)s0 * 128 + c);
        unsigned int u1 = *(const unsigned int*)(xbf + (size_t)s1 * 128 + c);
        float vA0 = sp0.x + sdp.x, vB0 = sp0.y + sdp.y;
        float vA1 = sp1.x + sdp.x, vB1 = sp1.y + sdp.y;
        vA0 = vA0 > 0.f ? vA0 : NEG_SLOPE * vA0;
        vB0 = vB0 > 0.f ? vB0 : NEG_SLOPE * vB0;
        vA1 = vA1 > 0.f ? vA1 : NEG_SLOPE * vA1;
        vB1 = vB1 > 0.f ? vB1 : NEG_SLOPE * vB1;
        float wA0 = __expf(vA0), wB0 = __expf(vB0);
        float wA1 = __expf(vA1), wB1 = __expf(vB1);
        wsA += wA0 + wA1;
        wsB += wB0 + wB1;
        float x00 = bf2f((unsigned short)(u0 & 0xffff));
        float x01 = bf2f((unsigned short)(u0 >> 16));
        float x10 = bf2f((unsigned short)(u1 & 0xffff));
        float x11 = bf2f((unsigned short)(u1 >> 16));
        aA0 = fmaf(x00, wA0, aA0); aA1 = fmaf(x01, wA0, aA1);
        aB0 = fmaf(x00, wB0, aB0); aB1 = fmaf(x01, wB0, aB1);
        aA0 = fmaf(x10, wA1, aA0); aA1 = fmaf(x11, wA1, aA1);
        aB0 = fmaf(x10, wB1, aB0); aB1 = fmaf(x11, wB1, aB1);
      }
      if (p < end) {
        int s0 = srcs[p];
        float2 sp0 = *(const float2*)(ssrc + (size_t)s0 * 8 + h0);
        unsigned int u0 = *(const unsigned int*)(xbf + (size_t)s0 * 128 + c);
        float vA0 = sp0.x + sdp.x, vB0 = sp0.y + sdp.y;
        vA0 = vA0 > 0.f ? vA0 : NEG_SLOPE * vA0;
        vB0 = vB0 > 0.f ? vB0 : NEG_SLOPE * vB0;
        float wA0 = __expf(vA0), wB0 = __expf(vB0);
        wsA += wA0;
        wsB += wB0;
        float x00 = bf2f((unsigned short)(u0 & 0xffff));
        float x01 = bf2f((unsigned short)(u0 >> 16));
        aA0 = fmaf(x00, wA0, aA0); aA1 = fmaf(x01, wA0, aA1);
        aB0 = fmaf(x00, wB0, aB0); aB1 = fmaf(x01, wB0, aB1);
      }
    }
    float invA = 1.0f / (wsA + 1e-16f);
    float invB = 1.0f / (wsB + 1e-16f);
    // swizzled LDS write (write key nl&15 == read key row&15)
    int gs = (g ^ (nl & 15)) << 3;
    unsigned int wA = (unsigned int)f2bf(aA0 * invA) |
                      ((unsigned int)f2bf(aA1 * invA) << 16);
    unsigned int wB = (unsigned int)f2bf(aB0 * invB) |
                      ((unsigned int)f2bf(aB1 * invB) << 16);
    *(unsigned int*)(aggT + (nl * 2 + 0) * 128 + gs + e) = wA;
    *(unsigned int*)(aggT + (nl * 2 + 1) * 128 + gs + e) = wB;
  }
  __syncthreads();

  // ---- Phase 2: aggT(head hl) @ W1 panel + bias -> h1n ----
#pragma unroll
  for (int rg = 0; rg < 4; ++rg) {
    int arow = rg * 16 + r;
    bf16x8 af[4];
#pragma unroll
    for (int ks = 0; ks < 4; ++ks)
      af[ks] = *(const bf16x8*)(aggT + (arow * 2 + hl) * 128 +
                                (((ks * 4 + q) ^ (arow & 15)) << 3));
    f32x4 acc[4] = {};
#pragma unroll
    for (int ks = 0; ks < 4; ++ks)
#pragma unroll
      for (int ni = 0; ni < 4; ++ni)
        acc[ni] = __builtin_amdgcn_mfma_f32_16x16x32_bf16(af[ks], bfr[ni][ks],
                                                          acc[ni], 0, 0, 0);
#pragma unroll
    for (int ni = 0; ni < 4; ++ni) {
      int col = hg * 128 + colh + ni * 16 + r;
      float bb = bf2f(b1[col]);
#pragma unroll
      for (int i = 0; i < 4; ++i) {
        int row = m0 + rg * 16 + q * 4 + i;
        h1n[(size_t)row * 1024 + col] = f2bf(acc[ni][i] + bb);
      }
    }
  }
}

// ---------------------------------------------------------------------------
// Layer-2 GEMM: h2 = ELU(BN(h1n)) @ W2. BM=64, BK=64, BN+ELU fused at
// LDS-write, 1-deep reg prefetch, direct fp32 epilogue, fused scores.
// ---------------------------------------------------------------------------
__global__ __launch_bounds__(256) void gemm2_bn(
    const unsigned short* __restrict__ A,    // h1n [MP][1024]
    const unsigned short* __restrict__ Bt,   // W2t [128][1024]
    float* __restrict__ C,                   // h2 [MP][128]
    const float* __restrict__ scale, const float* __restrict__ shift,
    const unsigned short* __restrict__ aScr,
    const unsigned short* __restrict__ aDcr,
    float* __restrict__ ssrc, float* __restrict__ sdst) {
  constexpr int K = 1024;
  constexpr int BK = 64;
  constexpr int LDA = BK + 8;
  __shared__ unsigned short As[64 * LDA];
  __shared__ unsigned short Bs[128 * LDA];
  __shared__ float sS[2][64];
  __shared__ float sD[2][64];

  const int m0 = blockIdx.x * 64;
  const int tid = threadIdx.x;
  const int wid = tid >> 6;
  const int lane = tid & 63;
  const int q = lane >> 4;
  const int r = lane & 15;
  const int wm = (wid >> 1) * 32;
  const int wn = (wid & 1) * 64;

  f32x4 acc[2][4] = {};

  const int row0 = tid >> 3;          // 0..31
  const int col0 = (tid & 7) * 8;     // 0..56

  bf16x8 ra[2], rb[4];
#pragma unroll
  for (int ca = 0; ca < 2; ++ca)
    ra[ca] = *(const bf16x8*)(A + (size_t)(m0 + row0 + ca * 32) * K + col0);
#pragma unroll
  for (int cb = 0; cb < 4; ++cb)
    rb[cb] = *(const bf16x8*)(Bt + (size_t)(row0 + cb * 32) * K + col0);

  for (int k0 = 0; k0 < K; k0 += BK) {
    float scv[8], shv[8];
    *(float4*)&scv[0] = *(const float4*)(scale + k0 + col0);
    *(float4*)&scv[4] = *(const float4*)(scale + k0 + col0 + 4);
    *(float4*)&shv[0] = *(const float4*)(shift + k0 + col0);
    *(float4*)&shv[4] = *(const float4*)(shift + k0 + col0 + 4);
#pragma unroll
    for (int ca = 0; ca < 2; ++ca) {
      union { bf16x8 v; unsigned short u[8]; } pk;
      pk.v = ra[ca];
#pragma unroll
      for (int j = 0; j < 8; ++j) {
        float f = bf2f(pk.u[j]) * scv[j] + shv[j];
        f = f > 0.f ? f : (__expf(f) - 1.0f);
        pk.u[j] = f2bf(f);
      }
      *(bf16x8*)(&As[(row0 + ca * 32) * LDA + col0]) = pk.v;
    }
#pragma unroll
    for (int cb = 0; cb < 4; ++cb)
      *(bf16x8*)(&Bs[(row0 + cb * 32) * LDA + col0]) = rb[cb];
    __syncthreads();

    int k1 = k0 + BK;
    if (k1 < K) {
#pragma unroll
      for (int ca = 0; ca < 2; ++ca)
        ra[ca] = *(const bf16x8*)(A + (size_t)(m0 + row0 + ca * 32) * K + k1 +
                                  col0);
#pragma unroll
      for (int cb = 0; cb < 4; ++cb)
        rb[cb] = *(const bf16x8*)(Bt + (size_t)(row0 + cb * 32) * K + k1 +
                                  col0);
    }

#pragma unroll
    for (int ks = 0; ks < BK; ks += 32) {
      bf16x8 af[2], bfv[4];
#pragma unroll
      for (int mi = 0; mi < 2; ++mi)
        af[mi] = *(const bf16x8*)(&As[(wm + mi * 16 + r) * LDA + ks + q * 8]);
#pragma unroll
      for (int ni = 0; ni < 4; ++ni)
        bfv[ni] = *(const bf16x8*)(&Bs[(wn + ni * 16 + r) * LDA + ks + q * 8]);
#pragma unroll
      for (int mi = 0; mi < 2; ++mi)
#pragma unroll
        for (int ni = 0; ni < 4; ++ni)
          acc[mi][ni] = __builtin_amdgcn_mfma_f32_16x16x32_bf16(
              af[mi], bfv[ni], acc[mi][ni], 0, 0, 0);
    }
    __syncthreads();
  }

#pragma unroll
  for (int mi = 0; mi < 2; ++mi)
#pragma unroll
    for (int ni = 0; ni < 4; ++ni)
#pragma unroll
      for (int i = 0; i < 4; ++i) {
        int row = m0 + wm + mi * 16 + q * 4 + i;
        int col = wn + ni * 16 + r;
        C[(size_t)row * 128 + col] = acc[mi][ni][i];
      }

  const int half = wid & 1;
  float aSv[4], aDv[4];
#pragma unroll
  for (int ni = 0; ni < 4; ++ni) {
    aSv[ni] = bf2f(aScr[wn + ni * 16 + r]);
    aDv[ni] = bf2f(aDcr[wn + ni * 16 + r]);
  }
#pragma unroll
  for (int mi = 0; mi < 2; ++mi) {
#pragma unroll
    for (int i = 0; i < 4; ++i) {
      float ps = 0.f, pd = 0.f;
#pragma unroll
      for (int ni = 0; ni < 4; ++ni) {
        float v = acc[mi][ni][i];
        ps += v * aSv[ni];
        pd += v * aDv[ni];
      }
      ps += __shfl_xor(ps, 1, 64); pd += __shfl_xor(pd, 1, 64);
      ps += __shfl_xor(ps, 2, 64); pd += __shfl_xor(pd, 2, 64);
      ps += __shfl_xor(ps, 4, 64); pd += __shfl_xor(pd, 4, 64);
      ps += __shfl_xor(ps, 8, 64); pd += __shfl_xor(pd, 8, 64);
      if (r == 0) {
        int rl = wm + mi * 16 + q * 4 + i;
        sS[half][rl] = ps;
        sD[half][rl] = pd;
      }
    }
  }
  __syncthreads();
  if (tid < 64) {
    ssrc[m0 + tid] = sS[0][tid] + sS[1][tid];
    sdst[m0 + tid] = sD[0][tid] + sD[1][tid];
  }
}

// ---------------------------------------------------------------------------
// CSR build over dst — parallel 3-phase scan.
// ---------------------------------------------------------------------------
__global__ __launch_bounds__(256) void count_dst(const int* __restrict__ eid,
                                                 int E, int* __restrict__ cnt) {
  int e = blockIdx.x * 256 + threadIdx.x;
  if (e < E) atomicAdd(&cnt[eid[e]], 1);
}

__global__ __launch_bounds__(256) void scan_p1(const int* __restrict__ cnt,
                                               int* __restrict__ bsum, int N) {
  __shared__ int sd[256];
  int b = blockIdx.x, t = threadIdx.x;
  int base = b * 2048;
  int s = 0;
  for (int i = t; i < 2048; i += 256) {
    int idx = base + i;
    if (idx < N) s += cnt[idx];
  }
  sd[t] = s;
  __syncthreads();
  for (int o = 128; o > 0; o >>= 1) {
    if (t < o) sd[t] += sd[t + o];
    __syncthreads();
  }
  if (t == 0) bsum[b] = sd[0];
}

__global__ __launch_bounds__(256) void scan_p2(int* __restrict__ bsum, int nb) {
  __shared__ int sd[256];
  int t = threadIdx.x;
  int own = (t < nb) ? bsum[t] : 0;
  sd[t] = own;
  __syncthreads();
  for (int o = 1; o < 256; o <<= 1) {
    int v = (t >= o) ? sd[t - o] : 0;
    __syncthreads();
    sd[t] += v;
    __syncthreads();
  }
  if (t < nb) bsum[t] = sd[t] - own;  // exclusive
}

__global__ __launch_bounds__(256) void scan_p3(
    const int* __restrict__ cnt, const int* __restrict__ bsum,
    int* __restrict__ offsets, int* __restrict__ cursor, int N) {
  __shared__ int sd[256];
  int b = blockIdx.x, t = threadIdx.x;
  int base = b * 2048 + t * 8;
  int c[8];
  int ts = 0;
#pragma unroll
  for (int j = 0; j < 8; ++j) {
    int idx = base + j;
    c[j] = (idx < N) ? cnt[idx] : 0;
    ts += c[j];
  }
  sd[t] = ts;
  __syncthreads();
  for (int o = 1; o < 256; o <<= 1) {
    int v = (t >= o) ? sd[t - o] : 0;
    __syncthreads();
    sd[t] += v;
    __syncthreads();
  }
  int run = bsum[b] + sd[t] - ts;
#pragma unroll
  for (int j = 0; j < 8; ++j) {
    int idx = base + j;
    if (idx < N) {
      offsets[idx] = run;
      cursor[idx] = run;
      run += c[j];
    }
  }
  if (b == gridDim.x - 1 && t == 255) offsets[N] = bsum[b] + sd[255];
}

__global__ __launch_bounds__(256) void scatter_src(
    const int* __restrict__ eis, const int* __restrict__ eid, int E,
    int* __restrict__ cursor, int* __restrict__ srcs) {
  int e = blockIdx.x * 256 + threadIdx.x;
  if (e >= E) return;
  int d = eid[e];
  int pos = atomicAdd(&cursor[d], 1);
  srcs[pos] = eis[e];
}

// ---------------------------------------------------------------------------
// BN stats, two-stage, ATOMIC-FREE. NSTAT=256.
// ---------------------------------------------------------------------------
__global__ __launch_bounds__(256) void bn_stats_part(
    const unsigned short* __restrict__ h1n, float* __restrict__ part, int N,
    int rowsPerBlock) {
  int b = blockIdx.x;
  int half = threadIdx.x >> 7;
  int t = threadIdx.x & 127;
  int c = t * 8;
  int r0 = b * rowsPerBlock;
  int r1 = min(r0 + rowsPerBlock, N);
  float s[8] = {0, 0, 0, 0, 0, 0, 0, 0};
  float q[8] = {0, 0, 0, 0, 0, 0, 0, 0};
  int r = r0 + half;
  for (; r + 2 < r1; r += 4) {
    union { bf16x8 v; unsigned short u[8]; } u0, u1;
    u0.v = *(const bf16x8*)(h1n + (size_t)r * 1024 + c);
    u1.v = *(const bf16x8*)(h1n + (size_t)(r + 2) * 1024 + c);
#pragma unroll
    for (int j = 0; j < 8; ++j) {
      float v0 = bf2f(u0.u[j]);
      float v1 = bf2f(u1.u[j]);
      s[j] += v0 + v1;
      q[j] = fmaf(v0, v0, q[j]);
      q[j] = fmaf(v1, v1, q[j]);
    }
  }
  for (; r < r1; r += 2) {
    union { bf16x8 v; unsigned short u[8]; } u0;
    u0.v = *(const bf16x8*)(h1n + (size_t)r * 1024 + c);
#pragma unroll
    for (int j = 0; j < 8; ++j) {
      float v0 = bf2f(u0.u[j]);
      s[j] += v0;
      q[j] = fmaf(v0, v0, q[j]);
    }
  }
  float* pb = part + ((size_t)b * 2 + half) * 2048;
#pragma unroll
  for (int j = 0; j < 8; ++j) {
    pb[c + j] = s[j];
    pb[1024 + c + j] = q[j];
  }
}

__global__ __launch_bounds__(256) void bn_reduce_finalize(
    const float* __restrict__ part, int nparts,
    const unsigned short* __restrict__ gamma,
    const unsigned short* __restrict__ beta, float* __restrict__ scale,
    float* __restrict__ shift, int N) {
  int c = blockIdx.x * 4 + (threadIdx.x >> 6);  // channel [0,1024)
  int lane = threadIdx.x & 63;
  float s = 0.f, q = 0.f;
  for (int b = lane; b < nparts; b += 64) {
    s += part[(size_t)b * 2048 + c];
    q += part[(size_t)b * 2048 + 1024 + c];
  }
#pragma unroll
  for (int o = 32; o > 0; o >>= 1) {
    s += __shfl_xor(s, o, 64);
    q += __shfl_xor(q, o, 64);
  }
  if (lane == 0) {
    float inv_n = 1.0f / (float)N;
    float mu = s * inv_n;
    float var = q * inv_n - mu * mu;
    float sc = bf2f(gamma[c]) * rsqrtf(var + BN_EPS);
    scale[c] = sc;
    shift[c] = bf2f(beta[c]) - mu * sc;
  }
}

// ---------------------------------------------------------------------------
// Layer-2 aggregation: wave per dst node (4 nodes / 256-thread block),
// lane owns 2 ch (float2; 64 lanes x 8 B = full 512-B row per load),
// 2-deep edge pipeline, weights inline, wave-uniform control flow.
// ---------------------------------------------------------------------------
__global__ __launch_bounds__(256) void agg2_csr(
    const int* __restrict__ offsets, const int* __restrict__ srcs,
    const float* __restrict__ h2, const float* __restrict__ ssrc,
    const float* __restrict__ sdst, const unsigned short* __restrict__ b2,
    void* __restrict__ out, const int* __restrict__ flags, int N) {
  int n = blockIdx.x * 4 + (threadIdx.x >> 6);
  if (n >= N) return;
  int c = (threadIdx.x & 63) * 2;
  int beg = offsets[n], end = offsets[n + 1];
  float sd = sdst[n];
  float a0 = 0.f, a1 = 0.f, wsum = 0.f;
  int p = beg;
  for (; p + 2 <= end; p += 2) {
    int s0 = srcs[p], s1 = srcs[p + 1];
    float v0 = ssrc[s0] + sd;
    float v1 = ssrc[s1] + sd;
    float2 u0 = *(const float2*)(h2 + (size_t)s0 * 128 + c);
    float2 u1 = *(const float2*)(h2 + (size_t)s1 * 128 + c);
    v0 = v0 > 0.f ? v0 : NEG_SLOPE * v0;
    v1 = v1 > 0.f ? v1 : NEG_SLOPE * v1;
    float w0 = __expf(v0), w1 = __expf(v1);
    wsum += w0 + w1;
    a0 = fmaf(u0.x, w0, a0);
    a1 = fmaf(u0.y, w0, a1);
    a0 = fmaf(u1.x, w1, a0);
    a1 = fmaf(u1.y, w1, a1);
  }
  if (p < end) {
    int s0 = srcs[p];
    float v0 = ssrc[s0] + sd;
    float2 u0 = *(const float2*)(h2 + (size_t)s0 * 128 + c);
    v0 = v0 > 0.f ? v0 : NEG_SLOPE * v0;
    float w0 = __expf(v0);
    wsum += w0;
    a0 = fmaf(u0.x, w0, a0);
    a1 = fmaf(u0.y, w0, a1);
  }
  float inv = 1.0f / (wsum + 1e-16f);
  unsigned int bb = *(const unsigned int*)(b2 + c);
  float r0 = a0 * inv + bf2f(bb & 0xffff);
  float r1 = a1 * inv + bf2f(bb >> 16);
  if (flags[0]) {
    unsigned int o = (unsigned int)f2bf(r0) | ((unsigned int)f2bf(r1) << 16);
    *(unsigned int*)((unsigned short*)out + (size_t)n * 128 + c) = o;
  } else {
    *(float2*)((float*)out + (size_t)n * 128 + c) = make_float2(r0, r1);
  }
}

// ---------------------------------------------------------------------------
extern "C" void kernel_launch(void* const* d_in, const int* in_sizes, int n_in,
                              void* d_out, int out_size, void* d_ws,
                              size_t ws_size, hipStream_t stream) {
  const void* x      = d_in[0];
  const int*  ei     = (const int*)d_in[1];
  const void* W1     = d_in[2];
  const void* a_src1 = d_in[3];
  const void* a_dst1 = d_in[4];
  const void* b1     = d_in[5];
  const void* gamma  = d_in[6];
  const void* beta   = d_in[7];
  const void* W2     = d_in[8];
  const void* a_src2 = d_in[9];
  const void* a_dst2 = d_in[10];
  const void* b2     = d_in[11];

  const int N = in_sizes[0] / 128;            // 50000
  const int E = in_sizes[1] / 2;              // 150000
  const int MP = ((N + 127) / 128) * 128;     // 50048 (mult of 128 and 64)
  const int NB = (N + 2047) / 2048;           // scan chunks
  const int NSTAT = 256;                      // bn stage-1 blocks
  const int RPB = (N + NSTAT - 1) / NSTAT;    // rows per stat block

  // ---- workspace layout (bytes) ----
  char* ws = (char*)d_ws;
  size_t off = 0;
  char* regA = ws + off;                       // old h1 region, 102.5 MB
  off += (size_t)MP * 1024 * 2;
  char* h1n_base = ws + off;
  unsigned short* h1n = (unsigned short*)h1n_base;   off += (size_t)MP * 1024 * 2;
  float* ssrc1 = (float*)(ws + off); off += (size_t)MP * 8 * 4;  // [MP][8]
  float* sdst1 = (float*)(ws + off); off += (size_t)MP * 8 * 4;  // [MP][8]
  int* offsets = (int*)(ws + off); off += ((size_t)(N + 1) * 4 + 63) & ~63ull;
  int* srcs    = (int*)(ws + off); off += (size_t)E * 4;
  float* part  = (float*)(ws + off); off += (size_t)NSTAT * 2 * 2048 * 4;  // 4 MB
  unsigned short* W1t = (unsigned short*)(ws + off); off += 131072 * 2;
  unsigned short* W2t = (unsigned short*)(ws + off); off += 131072 * 2;
  unsigned short* as1c = (unsigned short*)(ws + off); off += 1024 * 2;
  unsigned short* ad1c = (unsigned short*)(ws + off); off += 1024 * 2;
  unsigned short* b1c  = (unsigned short*)(ws + off); off += 1024 * 2;
  unsigned short* gmc  = (unsigned short*)(ws + off); off += 1024 * 2;
  unsigned short* btc  = (unsigned short*)(ws + off); off += 1024 * 2;
  unsigned short* as2c = (unsigned short*)(ws + off); off += 128 * 2;
  unsigned short* ad2c = (unsigned short*)(ws + off); off += 128 * 2;
  unsigned short* b2c  = (unsigned short*)(ws + off); off += 128 * 2;
  float* scale = (float*)(ws + off); off += 1024 * 4;
  float* shift = (float*)(ws + off); off += 1024 * 4;
  float* vsrc  = (float*)(ws + off); off += 128 * 8 * 4;
  float* vdst  = (float*)(ws + off); off += 128 * 8 * 4;
  int* bsum    = (int*)(ws + off); off += 256 * 4;
  int* flags   = (int*)(ws + off); off += 64;
  // Region-A occupants: x_bf (12.8 MB @ +0), h2 (25.6 MB fp32 @ +32 MB;
  // written by gemm2 after x_bf is dead).
  unsigned short* x_bf = (unsigned short*)regA;
  float* h2    = (float*)(regA + (32u << 20));
  // eis/eid/cnt/cursor alias h1n's dead region (all consumed before
  // agg1_fused writes h1n).
  int* eis    = (int*)(h1n_base + (16u << 20));
  int* eid    = eis + E;
  int* cnt    = eid + E;
  int* cursor = cnt + N;
  float* ssrc2 = ssrc1;  // flat [MP]; [MP][8] layout dead after agg1_fused
  float* sdst2 = sdst1;

  // ---- detection + canonicalization ----
  detect_kernel<<<1, 256, 0, stream>>>((const unsigned int*)x,
                                       (const unsigned int*)ei, E, flags);
  canon_x8<<<(MP * 128 / 8 + 255) / 256, 256, 0, stream>>>(x, x_bf, N * 128,
                                                           MP * 128, flags);
  canon_w_t<<<(131072 + 255) / 256, 256, 0, stream>>>(W1, W1t, 128, 1024, flags);
  canon_w_t<<<(131072 + 255) / 256, 256, 0, stream>>>(W2, W2t, 1024, 128, flags);
  canon_params<<<8, 1024, 0, stream>>>(a_src1, a_dst1, b1, gamma, beta, a_src2,
                                       a_dst2, b2, as1c, ad1c, b1c, gmc, btc,
                                       as2c, ad2c, b2c, flags);
  canon_idx<<<(E + 255) / 256, 256, 0, stream>>>(ei, eis, eid, E, flags);

  // ---- zero init ----
  hipMemsetAsync(cnt, 0, (size_t)N * 4, stream);

  // ---- CSR build (dst-sorted), parallel scan ----
  count_dst<<<(E + 255) / 256, 256, 0, stream>>>(eid, E, cnt);
  scan_p1<<<NB, 256, 0, stream>>>(cnt, bsum, N);
  scan_p2<<<1, 256, 0, stream>>>(bsum, NB);
  scan_p3<<<NB, 256, 0, stream>>>(cnt, bsum, offsets, cursor, N);
  scatter_src<<<(E + 255) / 256, 256, 0, stream>>>(eis, eid, E, cursor, srcs);

  // ---- Layer-1 scores WITHOUT h1 (linearity: s = x @ (W1^T a)) ----
  score_v<<<1, 128, 0, stream>>>(W1, as1c, ad1c, vsrc, vdst, flags);
  score_apply<<<(N + 15) / 16, 256, 0, stream>>>(x_bf, vsrc, vdst, ssrc1,
                                                 sdst1, N);

  // ---- Layer-1 fused aggregate+GEMM: h1n = (sum alpha x[src]) @ W1 + b1 ----
  agg1_fused<<<(MP / 64) * 4, 256, 0, stream>>>(offsets, srcs, x_bf, ssrc1,
                                                sdst1, W1t, b1c, h1n, N);

  // ---- BN stats (two-stage, atomic-free; stage 2 wave-per-channel) ----
  bn_stats_part<<<NSTAT, 256, 0, stream>>>(h1n, part, N, RPB);
  bn_reduce_finalize<<<256, 256, 0, stream>>>(part, NSTAT * 2, gmc, btc, scale,
                                              shift, N);

  // ---- Layer 2: h2 = ELU(BN(h1n)) @ W2 (BK=64, fused BN+ELU + scores) ----
  gemm2_bn<<<MP / 64, 256, 0, stream>>>(h1n, W2t, h2, scale, shift, as2c,
                                        ad2c, ssrc2, sdst2);
  agg2_csr<<<(N + 3) / 4, 256, 0, stream>>>(offsets, srcs, h2, ssrc2, sdst2,
                                            b2c, d_out, flags, N);
}

// Round 12
// 348.612 us; speedup vs baseline: 1.3927x; 1.3927x over previous
//
#include <hip/hip_runtime.h>
#include <hip/hip_bf16.h>
#include <math.h>

#define NEG_SLOPE 0.2f
#define BN_EPS 1e-5f

typedef short bf16x8 __attribute__((ext_vector_type(8)));
typedef float f32x4 __attribute__((ext_vector_type(4)));

// ---- bf16 helpers (raw ushort payload) ------------------------------------
__device__ __forceinline__ float bf2f(unsigned short u) {
  union { unsigned int i; float f; } v;
  v.i = ((unsigned int)u) << 16;
  return v.f;
}
__device__ __forceinline__ unsigned short f2bf(float f) {
  union { unsigned int i; float f; } v;
  v.f = f;
  unsigned int i = v.i;
  unsigned int r = (i + 0x7fffu + ((i >> 16) & 1u)) >> 16;  // RNE
  return (unsigned short)r;
}

// ---------------------------------------------------------------------------
// Dtype detection: flags[0]=1 if floats are bf16; flags[1]=1 if idx int64.
// ---------------------------------------------------------------------------
__global__ __launch_bounds__(256) void detect_kernel(
    const unsigned int* __restrict__ xw, const unsigned int* __restrict__ eiw,
    int E, int* __restrict__ flags) {
  __shared__ int cnt[2];
  if (threadIdx.x < 2) cnt[threadIdx.x] = 0;
  __syncthreads();
  int t = threadIdx.x;
  int inrange = 0;
  for (int i = t; i < 2048; i += 256) {
    unsigned int e = (xw[i] >> 7) & 0xFFu;
    inrange += (e >= 100u && e <= 135u) ? 1 : 0;
  }
  atomicAdd(&cnt[0], inrange);
  int M = min(1024, E / 2);
  int zeros = 0;
  for (int i = t; i < M; i += 256) zeros += (eiw[2 * i + 1] == 0u) ? 1 : 0;
  atomicAdd(&cnt[1], zeros);
  __syncthreads();
  if (t == 0) {
    flags[0] = (cnt[0] > 1536) ? 1 : 0;
    flags[1] = (cnt[1] > M / 2) ? 1 : 0;
  }
}

// Vectorized x canonicalization: 8 elems/thread (16-B bf16 stores).
__global__ __launch_bounds__(256) void canon_x8(
    const void* __restrict__ src, unsigned short* __restrict__ dst, int n_real,
    int n_total, const int* __restrict__ flags) {
  int i = (blockIdx.x * 256 + threadIdx.x) * 8;
  if (i >= n_total) return;
  union { bf16x8 v; unsigned short u[8]; } o;
  if (i < n_real) {
    if (flags[0]) {
      o.v = *(const bf16x8*)((const unsigned short*)src + i);
    } else {
      const float4* f = (const float4*)((const float*)src + i);
      float4 f0 = f[0];
      float4 f1 = f[1];
      o.u[0] = f2bf(f0.x); o.u[1] = f2bf(f0.y);
      o.u[2] = f2bf(f0.z); o.u[3] = f2bf(f0.w);
      o.u[4] = f2bf(f1.x); o.u[5] = f2bf(f1.y);
      o.u[6] = f2bf(f1.z); o.u[7] = f2bf(f1.w);
    }
  } else {
#pragma unroll
    for (int j = 0; j < 8; ++j) o.u[j] = 0;
  }
  *(bf16x8*)(dst + i) = o.v;
}

// W [K][N] -> Wt [N][K] bf16.
__global__ __launch_bounds__(256) void canon_w_t(
    const void* __restrict__ src, unsigned short* __restrict__ dst, int Kdim,
    int Ndim, const int* __restrict__ flags) {
  int i = blockIdx.x * 256 + threadIdx.x;
  if (i >= Kdim * Ndim) return;
  int k = i / Ndim, n = i - k * Ndim;
  unsigned short v = flags[0] ? ((const unsigned short*)src)[i]
                              : f2bf(((const float*)src)[i]);
  dst[(size_t)n * Kdim + k] = v;
}

__global__ __launch_bounds__(1024) void canon_params(
    const void* s0, const void* s1, const void* s2, const void* s3,
    const void* s4, const void* s5, const void* s6, const void* s7,
    unsigned short* d0, unsigned short* d1, unsigned short* d2,
    unsigned short* d3, unsigned short* d4, unsigned short* d5,
    unsigned short* d6, unsigned short* d7, const int* __restrict__ flags) {
  int b = blockIdx.x, t = threadIdx.x;
  const void* s;
  unsigned short* d;
  int n;
  switch (b) {
    case 0: s = s0; d = d0; n = 1024; break;
    case 1: s = s1; d = d1; n = 1024; break;
    case 2: s = s2; d = d2; n = 1024; break;
    case 3: s = s3; d = d3; n = 1024; break;
    case 4: s = s4; d = d4; n = 1024; break;
    case 5: s = s5; d = d5; n = 128; break;
    case 6: s = s6; d = d6; n = 128; break;
    default: s = s7; d = d7; n = 128; break;
  }
  if (t < n)
    d[t] = flags[0] ? ((const unsigned short*)s)[t]
                    : f2bf(((const float*)s)[t]);
}

__global__ __launch_bounds__(256) void canon_idx(
    const int* __restrict__ ei, int* __restrict__ eis, int* __restrict__ eid,
    int E, const int* __restrict__ flags) {
  int e = blockIdx.x * 256 + threadIdx.x;
  if (e >= E) return;
  if (flags[1]) {
    eis[e] = ei[2 * (size_t)e];
    eid[e] = ei[2 * (size_t)E + 2 * (size_t)e];
  } else {
    eis[e] = ei[e];
    eid[e] = ei[E + e];
  }
}

// ---------------------------------------------------------------------------
// Layer-1 GEMM, K-resident: one block per 64-row A-tile. A (K=128) staged
// ONCE into LDS (XOR-swizzled); loop over 8 col panels (= heads), staging
// each 128x128 W1t panel with early-issued register prefetch.
// Scores accumulate in LDS sAll[64][8] (INTERLEAVED [row][head] layout) and
// are written as ONE contiguous 2-KB float4 burst at the end — coalesced
// write AND 1-cache-line-per-src gather in agg1 (r5 plane layout cost
// +39 MB FETCH in agg1; r6 confirmed interleaved fixes it: 191->157 MB).
// ---------------------------------------------------------------------------
__global__ __launch_bounds__(256) void gemm1_fused(
    const unsigned short* __restrict__ A,    // x_bf [MP][128]
    const unsigned short* __restrict__ Bt,   // W1t  [1024][128]
    unsigned short* __restrict__ C,          // h1   [MP][1024]
    const unsigned short* __restrict__ aScr, // a_src1 [1024]
    const unsigned short* __restrict__ aDcr, // a_dst1 [1024]
    float* __restrict__ ssrc,                // [MP][8]
    float* __restrict__ sdst,                // [MP][8]
    int MP) {
  __shared__ unsigned short As[64 * 128];   // 16 KB, swizzled
  __shared__ unsigned short Bs[128 * 128];  // 32 KB, swizzled
  __shared__ float sAll[64][8];             // 2 KB
  __shared__ float dAll[64][8];             // 2 KB

  const int tid = threadIdx.x;
  const int wid = tid >> 6;
  const int lane = tid & 63;
  const int q = lane >> 4;
  const int r = lane & 15;
  const int wm = wid * 16;  // wave's 16 rows
  const int m0 = blockIdx.x * 64;

  const int arow = tid >> 4;   // 0..15
  const int ag = tid & 15;     // granule 0..15

  bf16x8 ra[4], rb[8];
#pragma unroll
  for (int j = 0; j < 4; ++j)
    ra[j] = *(const bf16x8*)(A + (size_t)(m0 + j * 16 + arow) * 128 + ag * 8);
#pragma unroll
  for (int j = 0; j < 8; ++j)
    rb[j] = *(const bf16x8*)(Bt + (size_t)(j * 16 + arow) * 128 + ag * 8);
#pragma unroll
  for (int j = 0; j < 4; ++j) {
    int row = j * 16 + arow;
    int gs = ag ^ (row & 15);
    *(bf16x8*)(As + row * 128 + gs * 8) = ra[j];
  }
#pragma unroll
  for (int j = 0; j < 8; ++j) {
    int row = j * 16 + arow;
    int gs = ag ^ (row & 15);
    *(bf16x8*)(Bs + row * 128 + gs * 8) = rb[j];
  }
  __syncthreads();

  for (int p = 0; p < 8; ++p) {
    if (p < 7) {
#pragma unroll
      for (int j = 0; j < 8; ++j)
        rb[j] = *(const bf16x8*)(Bt +
                 (size_t)((p + 1) * 128 + j * 16 + arow) * 128 + ag * 8);
    }
    f32x4 acc[8] = {};
#pragma unroll
    for (int ks = 0; ks < 4; ++ks) {
      bf16x8 af = *(const bf16x8*)(As + (wm + r) * 128 +
                                   (((ks * 4 + q) ^ r) << 3));
#pragma unroll
      for (int ni = 0; ni < 8; ++ni) {
        bf16x8 bf = *(const bf16x8*)(Bs + (ni * 16 + r) * 128 +
                                     (((ks * 4 + q) ^ r) << 3));
        acc[ni] = __builtin_amdgcn_mfma_f32_16x16x32_bf16(af, bf, acc[ni],
                                                          0, 0, 0);
      }
    }
#pragma unroll
    for (int ni = 0; ni < 8; ++ni)
#pragma unroll
      for (int i = 0; i < 4; ++i)
        C[(size_t)(m0 + wm + q * 4 + i) * 1024 + p * 128 + ni * 16 + r] =
            f2bf(acc[ni][i]);
    // scores for this panel (= head p) -> LDS accumulate
    float aSv[8], aDv[8];
#pragma unroll
    for (int ni = 0; ni < 8; ++ni) {
      aSv[ni] = bf2f(aScr[p * 128 + ni * 16 + r]);
      aDv[ni] = bf2f(aDcr[p * 128 + ni * 16 + r]);
    }
#pragma unroll
    for (int i = 0; i < 4; ++i) {
      float ps = 0.f, pd = 0.f;
#pragma unroll
      for (int ni = 0; ni < 8; ++ni) {
        ps += acc[ni][i] * aSv[ni];
        pd += acc[ni][i] * aDv[ni];
      }
      ps += __shfl_xor(ps, 1, 64); pd += __shfl_xor(pd, 1, 64);
      ps += __shfl_xor(ps, 2, 64); pd += __shfl_xor(pd, 2, 64);
      ps += __shfl_xor(ps, 4, 64); pd += __shfl_xor(pd, 4, 64);
      ps += __shfl_xor(ps, 8, 64); pd += __shfl_xor(pd, 8, 64);
      if (r == 0) {
        sAll[wm + q * 4 + i][p] = ps;
        dAll[wm + q * 4 + i][p] = pd;
      }
    }
    __syncthreads();  // all waves done reading Bs(p)
    if (p < 7) {
#pragma unroll
      for (int j = 0; j < 8; ++j) {
        int row = j * 16 + arow;
        int gs = ag ^ (row & 15);
        *(bf16x8*)(Bs + row * 128 + gs * 8) = rb[j];
      }
      __syncthreads();
    }
  }
  __syncthreads();  // sAll/dAll complete across waves
  if (tid < 128) {
    float4 v = *((const float4*)&sAll[0][0] + tid);
    *((float4*)(ssrc + (size_t)m0 * 8) + tid) = v;
  } else {
    float4 v = *((const float4*)&dAll[0][0] + (tid - 128));
    *((float4*)(sdst + (size_t)m0 * 8) + (tid - 128)) = v;
  }
}

// ---------------------------------------------------------------------------
// Layer-2 GEMM: h2 = ELU(BN(h1n)) @ W2. BM=64, BK=64, BN+ELU fused at
// LDS-write, 1-deep reg prefetch, direct fp32 epilogue, fused scores.
// ---------------------------------------------------------------------------
__global__ __launch_bounds__(256) void gemm2_bn(
    const unsigned short* __restrict__ A,    // h1n [MP][1024]
    const unsigned short* __restrict__ Bt,   // W2t [128][1024]
    float* __restrict__ C,                   // h2 [MP][128]
    const float* __restrict__ scale, const float* __restrict__ shift,
    const unsigned short* __restrict__ aScr,
    const unsigned short* __restrict__ aDcr,
    float* __restrict__ ssrc, float* __restrict__ sdst) {
  constexpr int K = 1024;
  constexpr int BK = 64;
  constexpr int LDA = BK + 8;
  __shared__ unsigned short As[64 * LDA];
  __shared__ unsigned short Bs[128 * LDA];
  __shared__ float sS[2][64];
  __shared__ float sD[2][64];

  const int m0 = blockIdx.x * 64;
  const int tid = threadIdx.x;
  const int wid = tid >> 6;
  const int lane = tid & 63;
  const int q = lane >> 4;
  const int r = lane & 15;
  const int wm = (wid >> 1) * 32;
  const int wn = (wid & 1) * 64;

  f32x4 acc[2][4] = {};

  const int row0 = tid >> 3;          // 0..31
  const int col0 = (tid & 7) * 8;     // 0..56

  bf16x8 ra[2], rb[4];
#pragma unroll
  for (int ca = 0; ca < 2; ++ca)
    ra[ca] = *(const bf16x8*)(A + (size_t)(m0 + row0 + ca * 32) * K + col0);
#pragma unroll
  for (int cb = 0; cb < 4; ++cb)
    rb[cb] = *(const bf16x8*)(Bt + (size_t)(row0 + cb * 32) * K + col0);

  for (int k0 = 0; k0 < K; k0 += BK) {
    float scv[8], shv[8];
    *(float4*)&scv[0] = *(const float4*)(scale + k0 + col0);
    *(float4*)&scv[4] = *(const float4*)(scale + k0 + col0 + 4);
    *(float4*)&shv[0] = *(const float4*)(shift + k0 + col0);
    *(float4*)&shv[4] = *(const float4*)(shift + k0 + col0 + 4);
#pragma unroll
    for (int ca = 0; ca < 2; ++ca) {
      union { bf16x8 v; unsigned short u[8]; } pk;
      pk.v = ra[ca];
#pragma unroll
      for (int j = 0; j < 8; ++j) {
        float f = bf2f(pk.u[j]) * scv[j] + shv[j];
        f = f > 0.f ? f : (__expf(f) - 1.0f);
        pk.u[j] = f2bf(f);
      }
      *(bf16x8*)(&As[(row0 + ca * 32) * LDA + col0]) = pk.v;
    }
#pragma unroll
    for (int cb = 0; cb < 4; ++cb)
      *(bf16x8*)(&Bs[(row0 + cb * 32) * LDA + col0]) = rb[cb];
    __syncthreads();

    int k1 = k0 + BK;
    if (k1 < K) {
#pragma unroll
      for (int ca = 0; ca < 2; ++ca)
        ra[ca] = *(const bf16x8*)(A + (size_t)(m0 + row0 + ca * 32) * K + k1 +
                                  col0);
#pragma unroll
      for (int cb = 0; cb < 4; ++cb)
        rb[cb] = *(const bf16x8*)(Bt + (size_t)(row0 + cb * 32) * K + k1 +
                                  col0);
    }

#pragma unroll
    for (int ks = 0; ks < BK; ks += 32) {
      bf16x8 af[2], bfv[4];
#pragma unroll
      for (int mi = 0; mi < 2; ++mi)
        af[mi] = *(const bf16x8*)(&As[(wm + mi * 16 + r) * LDA + ks + q * 8]);
#pragma unroll
      for (int ni = 0; ni < 4; ++ni)
        bfv[ni] = *(const bf16x8*)(&Bs[(wn + ni * 16 + r) * LDA + ks + q * 8]);
#pragma unroll
      for (int mi = 0; mi < 2; ++mi)
#pragma unroll
        for (int ni = 0; ni < 4; ++ni)
          acc[mi][ni] = __builtin_amdgcn_mfma_f32_16x16x32_bf16(
              af[mi], bfv[ni], acc[mi][ni], 0, 0, 0);
    }
    __syncthreads();
  }

#pragma unroll
  for (int mi = 0; mi < 2; ++mi)
#pragma unroll
    for (int ni = 0; ni < 4; ++ni)
#pragma unroll
      for (int i = 0; i < 4; ++i) {
        int row = m0 + wm + mi * 16 + q * 4 + i;
        int col = wn + ni * 16 + r;
        C[(size_t)row * 128 + col] = acc[mi][ni][i];
      }

  const int half = wid & 1;
  float aSv[4], aDv[4];
#pragma unroll
  for (int ni = 0; ni < 4; ++ni) {
    aSv[ni] = bf2f(aScr[wn + ni * 16 + r]);
    aDv[ni] = bf2f(aDcr[wn + ni * 16 + r]);
  }
#pragma unroll
  for (int mi = 0; mi < 2; ++mi) {
#pragma unroll
    for (int i = 0; i < 4; ++i) {
      float ps = 0.f, pd = 0.f;
#pragma unroll
      for (int ni = 0; ni < 4; ++ni) {
        float v = acc[mi][ni][i];
        ps += v * aSv[ni];
        pd += v * aDv[ni];
      }
      ps += __shfl_xor(ps, 1, 64); pd += __shfl_xor(pd, 1, 64);
      ps += __shfl_xor(ps, 2, 64); pd += __shfl_xor(pd, 2, 64);
      ps += __shfl_xor(ps, 4, 64); pd += __shfl_xor(pd, 4, 64);
      ps += __shfl_xor(ps, 8, 64); pd += __shfl_xor(pd, 8, 64);
      if (r == 0) {
        int rl = wm + mi * 16 + q * 4 + i;
        sS[half][rl] = ps;
        sD[half][rl] = pd;
      }
    }
  }
  __syncthreads();
  if (tid < 64) {
    ssrc[m0 + tid] = sS[0][tid] + sS[1][tid];
    sdst[m0 + tid] = sD[0][tid] + sD[1][tid];
  }
}

// ---------------------------------------------------------------------------
// CSR build over dst — parallel 3-phase scan.
// ---------------------------------------------------------------------------
__global__ __launch_bounds__(256) void count_dst(const int* __restrict__ eid,
                                                 int E, int* __restrict__ cnt) {
  int e = blockIdx.x * 256 + threadIdx.x;
  if (e < E) atomicAdd(&cnt[eid[e]], 1);
}

__global__ __launch_bounds__(256) void scan_p1(const int* __restrict__ cnt,
                                               int* __restrict__ bsum, int N) {
  __shared__ int sd[256];
  int b = blockIdx.x, t = threadIdx.x;
  int base = b * 2048;
  int s = 0;
  for (int i = t; i < 2048; i += 256) {
    int idx = base + i;
    if (idx < N) s += cnt[idx];
  }
  sd[t] = s;
  __syncthreads();
  for (int o = 128; o > 0; o >>= 1) {
    if (t < o) sd[t] += sd[t + o];
    __syncthreads();
  }
  if (t == 0) bsum[b] = sd[0];
}

__global__ __launch_bounds__(256) void scan_p2(int* __restrict__ bsum, int nb) {
  __shared__ int sd[256];
  int t = threadIdx.x;
  int own = (t < nb) ? bsum[t] : 0;
  sd[t] = own;
  __syncthreads();
  for (int o = 1; o < 256; o <<= 1) {
    int v = (t >= o) ? sd[t - o] : 0;
    __syncthreads();
    sd[t] += v;
    __syncthreads();
  }
  if (t < nb) bsum[t] = sd[t] - own;  // exclusive
}

__global__ __launch_bounds__(256) void scan_p3(
    const int* __restrict__ cnt, const int* __restrict__ bsum,
    int* __restrict__ offsets, int* __restrict__ cursor, int N) {
  __shared__ int sd[256];
  int b = blockIdx.x, t = threadIdx.x;
  int base = b * 2048 + t * 8;
  int c[8];
  int ts = 0;
#pragma unroll
  for (int j = 0; j < 8; ++j) {
    int idx = base + j;
    c[j] = (idx < N) ? cnt[idx] : 0;
    ts += c[j];
  }
  sd[t] = ts;
  __syncthreads();
  for (int o = 1; o < 256; o <<= 1) {
    int v = (t >= o) ? sd[t - o] : 0;
    __syncthreads();
    sd[t] += v;
    __syncthreads();
  }
  int run = bsum[b] + sd[t] - ts;
#pragma unroll
  for (int j = 0; j < 8; ++j) {
    int idx = base + j;
    if (idx < N) {
      offsets[idx] = run;
      cursor[idx] = run;
      run += c[j];
    }
  }
  if (b == gridDim.x - 1 && t == 255) offsets[N] = bsum[b] + sd[255];
}

__global__ __launch_bounds__(256) void scatter_src(
    const int* __restrict__ eis, const int* __restrict__ eid, int E,
    int* __restrict__ cursor, int* __restrict__ srcs) {
  int e = blockIdx.x * 256 + threadIdx.x;
  if (e >= E) return;
  int d = eid[e];
  int pos = atomicAdd(&cursor[d], 1);
  srcs[pos] = eis[e];
}

// ---------------------------------------------------------------------------
// Layer-1 aggregation: wave per dst node (4 nodes / 256-thread block).
// Lane owns 16 ch: [lane*8, +8) head hA=lane>>4, and [512+lane*8, +8) head
// hA+4. Edge weights computed INLINE from INTERLEAVED scores ssrc[s*8+h]
// (one 32-B line per src). 2-edge pipeline x 2 half-rows = 4 independent
// 16-B loads in flight per lane. NO BN fusion (r6: LDS reduce cost
// occupancy 62->35% and +44 us; separate bn_stats_part is cheaper).
// ---------------------------------------------------------------------------
__global__ __launch_bounds__(256) void agg1_csr(
    const int* __restrict__ offsets, const int* __restrict__ srcs,
    const unsigned short* __restrict__ h1, const float* __restrict__ ssrc,
    const float* __restrict__ sdst, const unsigned short* __restrict__ b1,
    unsigned short* __restrict__ h1n, int N) {
  int n = blockIdx.x * 4 + (threadIdx.x >> 6);
  if (n >= N) return;
  int lane = threadIdx.x & 63;
  int c0 = lane * 8;
  int c1 = 512 + c0;
  int hA = lane >> 4;
  int beg = offsets[n], end = offsets[n + 1];
  float sdA = sdst[n * 8 + hA];
  float sdB = sdst[n * 8 + hA + 4];
  float accA[8] = {}, accB[8] = {};
  float wsA = 0.f, wsB = 0.f;
  int p = beg;
  for (; p + 2 <= end; p += 2) {
    int s0 = srcs[p], s1 = srcs[p + 1];
    float vA0 = ssrc[s0 * 8 + hA] + sdA;
    float vB0 = ssrc[s0 * 8 + hA + 4] + sdB;
    float vA1 = ssrc[s1 * 8 + hA] + sdA;
    float vB1 = ssrc[s1 * 8 + hA + 4] + sdB;
    union { bf16x8 v; unsigned short u[8]; } uA0, uB0, uA1, uB1;
    uA0.v = *(const bf16x8*)(h1 + (size_t)s0 * 1024 + c0);
    uB0.v = *(const bf16x8*)(h1 + (size_t)s0 * 1024 + c1);
    uA1.v = *(const bf16x8*)(h1 + (size_t)s1 * 1024 + c0);
    uB1.v = *(const bf16x8*)(h1 + (size_t)s1 * 1024 + c1);
    vA0 = vA0 > 0.f ? vA0 : NEG_SLOPE * vA0;
    vB0 = vB0 > 0.f ? vB0 : NEG_SLOPE * vB0;
    vA1 = vA1 > 0.f ? vA1 : NEG_SLOPE * vA1;
    vB1 = vB1 > 0.f ? vB1 : NEG_SLOPE * vB1;
    float wA0 = __expf(vA0), wB0 = __expf(vB0);
    float wA1 = __expf(vA1), wB1 = __expf(vB1);
    wsA += wA0 + wA1;
    wsB += wB0 + wB1;
#pragma unroll
    for (int j = 0; j < 8; ++j) {
      accA[j] = fmaf(bf2f(uA0.u[j]), wA0, accA[j]);
      accB[j] = fmaf(bf2f(uB0.u[j]), wB0, accB[j]);
      accA[j] = fmaf(bf2f(uA1.u[j]), wA1, accA[j]);
      accB[j] = fmaf(bf2f(uB1.u[j]), wB1, accB[j]);
    }
  }
  if (p < end) {
    int s0 = srcs[p];
    float vA0 = ssrc[s0 * 8 + hA] + sdA;
    float vB0 = ssrc[s0 * 8 + hA + 4] + sdB;
    union { bf16x8 v; unsigned short u[8]; } uA0, uB0;
    uA0.v = *(const bf16x8*)(h1 + (size_t)s0 * 1024 + c0);
    uB0.v = *(const bf16x8*)(h1 + (size_t)s0 * 1024 + c1);
    vA0 = vA0 > 0.f ? vA0 : NEG_SLOPE * vA0;
    vB0 = vB0 > 0.f ? vB0 : NEG_SLOPE * vB0;
    float wA0 = __expf(vA0), wB0 = __expf(vB0);
    wsA += wA0;
    wsB += wB0;
#pragma unroll
    for (int j = 0; j < 8; ++j) {
      accA[j] = fmaf(bf2f(uA0.u[j]), wA0, accA[j]);
      accB[j] = fmaf(bf2f(uB0.u[j]), wB0, accB[j]);
    }
  }
  float invA = 1.0f / (wsA + 1e-16f);
  float invB = 1.0f / (wsB + 1e-16f);
  union { bf16x8 v; unsigned short u[8]; } bA, bB, oA, oB;
  bA.v = *(const bf16x8*)(b1 + c0);
  bB.v = *(const bf16x8*)(b1 + c1);
#pragma unroll
  for (int j = 0; j < 8; ++j) {
    oA.u[j] = f2bf(accA[j] * invA + bf2f(bA.u[j]));
    oB.u[j] = f2bf(accB[j] * invB + bf2f(bB.u[j]));
  }
  *(bf16x8*)(h1n + (size_t)n * 1024 + c0) = oA.v;
  *(bf16x8*)(h1n + (size_t)n * 1024 + c1) = oB.v;
}

// ---------------------------------------------------------------------------
// BN stats, two-stage, ATOMIC-FREE. Stage 1: 16-B bf16x8 loads, 8 ch/thread,
// two half-blocks interleave rows; each half writes its own part slice.
// ---------------------------------------------------------------------------
__global__ __launch_bounds__(256) void bn_stats_part(
    const unsigned short* __restrict__ h1n, float* __restrict__ part, int N,
    int rowsPerBlock) {
  int b = blockIdx.x;
  int half = threadIdx.x >> 7;
  int t = threadIdx.x & 127;
  int c = t * 8;
  int r0 = b * rowsPerBlock;
  int r1 = min(r0 + rowsPerBlock, N);
  float s[8] = {0, 0, 0, 0, 0, 0, 0, 0};
  float q[8] = {0, 0, 0, 0, 0, 0, 0, 0};
  int r = r0 + half;
  for (; r + 2 < r1; r += 4) {
    union { bf16x8 v; unsigned short u[8]; } u0, u1;
    u0.v = *(const bf16x8*)(h1n + (size_t)r * 1024 + c);
    u1.v = *(const bf16x8*)(h1n + (size_t)(r + 2) * 1024 + c);
#pragma unroll
    for (int j = 0; j < 8; ++j) {
      float v0 = bf2f(u0.u[j]);
      float v1 = bf2f(u1.u[j]);
      s[j] += v0 + v1;
      q[j] = fmaf(v0, v0, q[j]);
      q[j] = fmaf(v1, v1, q[j]);
    }
  }
  for (; r < r1; r += 2) {
    union { bf16x8 v; unsigned short u[8]; } u0;
    u0.v = *(const bf16x8*)(h1n + (size_t)r * 1024 + c);
#pragma unroll
    for (int j = 0; j < 8; ++j) {
      float v0 = bf2f(u0.u[j]);
      s[j] += v0;
      q[j] = fmaf(v0, v0, q[j]);
    }
  }
  float* pb = part + ((size_t)b * 2 + half) * 2048;
#pragma unroll
  for (int j = 0; j < 8; ++j) {
    pb[c + j] = s[j];
    pb[1024 + c + j] = q[j];
  }
}

__global__ __launch_bounds__(256) void bn_reduce_finalize(
    const float* __restrict__ part, int nparts,
    const unsigned short* __restrict__ gamma,
    const unsigned short* __restrict__ beta, float* __restrict__ scale,
    float* __restrict__ shift, int N) {
  int c = blockIdx.x * 4 + (threadIdx.x >> 6);  // channel [0,1024)
  int lane = threadIdx.x & 63;
  float s = 0.f, q = 0.f;
  for (int b = lane; b < nparts; b += 64) {
    s += part[(size_t)b * 2048 + c];
    q += part[(size_t)b * 2048 + 1024 + c];
  }
#pragma unroll
  for (int o = 32; o > 0; o >>= 1) {
    s += __shfl_xor(s, o, 64);
    q += __shfl_xor(q, o, 64);
  }
  if (lane == 0) {
    float inv_n = 1.0f / (float)N;
    float mu = s * inv_n;
    float var = q * inv_n - mu * mu;
    float sc = bf2f(gamma[c]) * rsqrtf(var + BN_EPS);
    scale[c] = sc;
    shift[c] = bf2f(beta[c]) - mu * sc;
  }
}

// ---------------------------------------------------------------------------
// Layer-2 aggregation: 8 dst nodes per 256-thread block (32 threads/node,
// float4 = 16 B/lane), 2-deep edge pipeline, weights computed inline.
// ---------------------------------------------------------------------------
__global__ __launch_bounds__(256) void agg2_csr(
    const int* __restrict__ offsets, const int* __restrict__ srcs,
    const float* __restrict__ h2, const float* __restrict__ ssrc,
    const float* __restrict__ sdst, const unsigned short* __restrict__ b2,
    void* __restrict__ out, const int* __restrict__ flags, int N) {
  int n = blockIdx.x * 8 + (threadIdx.x >> 5);
  if (n >= N) return;
  int c = (threadIdx.x & 31) * 4;
  int beg = offsets[n], end = offsets[n + 1];
  float sd = sdst[n];
  float a0 = 0.f, a1 = 0.f, a2 = 0.f, a3 = 0.f, wsum = 0.f;
  int p = beg;
  for (; p + 2 <= end; p += 2) {
    int s0 = srcs[p], s1 = srcs[p + 1];
    float v0 = ssrc[s0] + sd;
    float v1 = ssrc[s1] + sd;
    float4 u0 = *(const float4*)(h2 + (size_t)s0 * 128 + c);
    float4 u1 = *(const float4*)(h2 + (size_t)s1 * 128 + c);
    v0 = v0 > 0.f ? v0 : NEG_SLOPE * v0;
    v1 = v1 > 0.f ? v1 : NEG_SLOPE * v1;
    float w0 = __expf(v0), w1 = __expf(v1);
    wsum += w0 + w1;
    a0 = fmaf(u0.x, w0, a0);
    a1 = fmaf(u0.y, w0, a1);
    a2 = fmaf(u0.z, w0, a2);
    a3 = fmaf(u0.w, w0, a3);
    a0 = fmaf(u1.x, w1, a0);
    a1 = fmaf(u1.y, w1, a1);
    a2 = fmaf(u1.z, w1, a2);
    a3 = fmaf(u1.w, w1, a3);
  }
  if (p < end) {
    int s0 = srcs[p];
    float v0 = ssrc[s0] + sd;
    float4 u0 = *(const float4*)(h2 + (size_t)s0 * 128 + c);
    v0 = v0 > 0.f ? v0 : NEG_SLOPE * v0;
    float w0 = __expf(v0);
    wsum += w0;
    a0 = fmaf(u0.x, w0, a0);
    a1 = fmaf(u0.y, w0, a1);
    a2 = fmaf(u0.z, w0, a2);
    a3 = fmaf(u0.w, w0, a3);
  }
  float inv = 1.0f / (wsum + 1e-16f);
  ushort4 bb = *(const ushort4*)(b2 + c);
  float r0 = a0 * inv + bf2f(bb.x);
  float r1 = a1 * inv + bf2f(bb.y);
  float r2 = a2 * inv + bf2f(bb.z);
  float r3 = a3 * inv + bf2f(bb.w);
  if (flags[0]) {
    ushort4 o;
    o.x = f2bf(r0); o.y = f2bf(r1); o.z = f2bf(r2); o.w = f2bf(r3);
    *(ushort4*)((unsigned short*)out + (size_t)n * 128 + c) = o;
  } else {
    *(float4*)((float*)out + (size_t)n * 128 + c) =
        make_float4(r0, r1, r2, r3);
  }
}

// ---------------------------------------------------------------------------
extern "C" void kernel_launch(void* const* d_in, const int* in_sizes, int n_in,
                              void* d_out, int out_size, void* d_ws,
                              size_t ws_size, hipStream_t stream) {
  const void* x      = d_in[0];
  const int*  ei     = (const int*)d_in[1];
  const void* W1     = d_in[2];
  const void* a_src1 = d_in[3];
  const void* a_dst1 = d_in[4];
  const void* b1     = d_in[5];
  const void* gamma  = d_in[6];
  const void* beta   = d_in[7];
  const void* W2     = d_in[8];
  const void* a_src2 = d_in[9];
  const void* a_dst2 = d_in[10];
  const void* b2     = d_in[11];

  const int N = in_sizes[0] / 128;            // 50000
  const int E = in_sizes[1] / 2;              // 150000
  const int MP = ((N + 127) / 128) * 128;     // 50048 (mult of 128 and 64)
  const int NB = (N + 2047) / 2048;           // scan chunks
  const int NSTAT = 256;                      // bn stage-1 blocks
  const int RPB = (N + NSTAT - 1) / NSTAT;    // rows per stat block

  // ---- workspace layout (bytes) ----
  char* ws = (char*)d_ws;
  size_t off = 0;
  unsigned short* h1  = (unsigned short*)(ws + off); off += (size_t)MP * 1024 * 2;
  char* h1n_base = ws + off;
  unsigned short* h1n = (unsigned short*)h1n_base;   off += (size_t)MP * 1024 * 2;
  float* ssrc1 = (float*)(ws + off); off += (size_t)MP * 8 * 4;  // [MP][8]
  float* sdst1 = (float*)(ws + off); off += (size_t)MP * 8 * 4;  // [MP][8]
  int* offsets = (int*)(ws + off); off += ((size_t)(N + 1) * 4 + 63) & ~63ull;
  int* srcs    = (int*)(ws + off); off += (size_t)E * 4;
  float* part  = (float*)(ws + off); off += (size_t)NSTAT * 2 * 2048 * 4;  // 4 MB
  unsigned short* W1t = (unsigned short*)(ws + off); off += 131072 * 2;
  unsigned short* W2t = (unsigned short*)(ws + off); off += 131072 * 2;
  unsigned short* as1c = (unsigned short*)(ws + off); off += 1024 * 2;
  unsigned short* ad1c = (unsigned short*)(ws + off); off += 1024 * 2;
  unsigned short* b1c  = (unsigned short*)(ws + off); off += 1024 * 2;
  unsigned short* gmc  = (unsigned short*)(ws + off); off += 1024 * 2;
  unsigned short* btc  = (unsigned short*)(ws + off); off += 1024 * 2;
  unsigned short* as2c = (unsigned short*)(ws + off); off += 128 * 2;
  unsigned short* ad2c = (unsigned short*)(ws + off); off += 128 * 2;
  unsigned short* b2c  = (unsigned short*)(ws + off); off += 128 * 2;
  float* scale = (float*)(ws + off); off += 1024 * 4;
  float* shift = (float*)(ws + off); off += 1024 * 4;
  int* bsum    = (int*)(ws + off); off += 256 * 4;
  int* flags   = (int*)(ws + off); off += 64;
  // Aliases into dead regions (h1n's first ~18.5 MB; all dead before agg1
  // writes h1n; h1n pad rows are at the END of the buffer).
  unsigned short* x_bf = (unsigned short*)h1n_base;
  int* eis    = (int*)(h1n_base + (16u << 20));
  int* eid    = eis + E;
  int* cnt    = eid + E;
  int* cursor = cnt + N;
  // h2 (fp32 [MP][128] = 25.6 MB) aliases h1 (dead after agg1).
  float* h2    = (float*)h1;
  float* ssrc2 = ssrc1;  // flat [MP]; [MP][8] layout dead after agg1
  float* sdst2 = sdst1;

  // ---- detection + canonicalization ----
  detect_kernel<<<1, 256, 0, stream>>>((const unsigned int*)x,
                                       (const unsigned int*)ei, E, flags);
  canon_x8<<<(MP * 128 / 8 + 255) / 256, 256, 0, stream>>>(x, x_bf, N * 128,
                                                           MP * 128, flags);
  canon_w_t<<<(131072 + 255) / 256, 256, 0, stream>>>(W1, W1t, 128, 1024, flags);
  canon_w_t<<<(131072 + 255) / 256, 256, 0, stream>>>(W2, W2t, 1024, 128, flags);
  canon_params<<<8, 1024, 0, stream>>>(a_src1, a_dst1, b1, gamma, beta, a_src2,
                                       a_dst2, b2, as1c, ad1c, b1c, gmc, btc,
                                       as2c, ad2c, b2c, flags);
  canon_idx<<<(E + 255) / 256, 256, 0, stream>>>(ei, eis, eid, E, flags);

  // ---- zero init ----
  hipMemsetAsync(cnt, 0, (size_t)N * 4, stream);
  hipMemsetAsync((char*)h1n + (size_t)N * 1024 * 2, 0,
                 (size_t)(MP - N) * 1024 * 2, stream);

  // ---- CSR build (dst-sorted), parallel scan ----
  count_dst<<<(E + 255) / 256, 256, 0, stream>>>(eid, E, cnt);
  scan_p1<<<NB, 256, 0, stream>>>(cnt, bsum, N);
  scan_p2<<<1, 256, 0, stream>>>(bsum, NB);
  scan_p3<<<NB, 256, 0, stream>>>(cnt, bsum, offsets, cursor, N);
  scatter_src<<<(E + 255) / 256, 256, 0, stream>>>(eis, eid, E, cursor, srcs);

  // ---- Layer 1: h1 = x @ W1, K-resident fused GEMM + interleaved scores ----
  gemm1_fused<<<MP / 64, 256, 0, stream>>>(x_bf, W1t, h1, as1c, ad1c, ssrc1,
                                           sdst1, MP);
  agg1_csr<<<(N + 3) / 4, 256, 0, stream>>>(offsets, srcs, h1, ssrc1, sdst1,
                                            b1c, h1n, N);

  // ---- BN stats (two-stage, atomic-free; stage 2 wave-per-channel) ----
  bn_stats_part<<<NSTAT, 256, 0, stream>>>(h1n, part, N, RPB);
  bn_reduce_finalize<<<256, 256, 0, stream>>>(part, NSTAT * 2, gmc, btc, scale,
                                              shift, N);

  // ---- Layer 2: h2 = ELU(BN(h1n)) @ W2 (BK=64, fused BN+ELU + scores) ----
  gemm2_bn<<<MP / 64, 256, 0, stream>>>(h1n, W2t, h2, scale, shift, as2c,
                                        ad2c, ssrc2, sdst2);
  agg2_csr<<<(N + 7) / 8, 256, 0, stream>>>(offsets, srcs, h2, ssrc2, sdst2,
                                            b2c, d_out, flags, N);
}